// Round 5
// baseline (339.606 us; speedup 1.0000x reference)
//
#include <hip/hip_runtime.h>

// Problem constants (from reference)
#define B_ 2048
#define S_ 200
#define D_ 128
#define H_ 64
#define ROWS (B_ * S_)       // 409600, divisible by 64
#define MASK_SCALE 1e10f

typedef __attribute__((ext_vector_type(8))) short short8_t;   // 8 bf16 in 4 VGPRs
typedef __attribute__((ext_vector_type(4))) float f32x4;

__device__ __forceinline__ unsigned short f2bf(float f) {
    unsigned u = __float_as_uint(f);
    unsigned r = (u + 0x7fffu + ((u >> 16) & 1u)) >> 16;   // round-to-nearest-even
    return (unsigned short)r;
}

// ---------------------------------------------------------------------------
// prep: blocks 0..31  -> wfrag: Wh(=W1+W2) bf16, MFMA B-fragment order
//       blocks 32..543-> tproj[b][h] = W_bias[h] + sum_d tgt[d]*(W3-W2)[d][h]
// ---------------------------------------------------------------------------
__global__ __launch_bounds__(256) void prep(const float* __restrict__ W,
                                            const float* __restrict__ W_bias,
                                            const float* __restrict__ target,
                                            unsigned short* __restrict__ wfrag,
                                            float* __restrict__ tproj) {
    const int blk = blockIdx.x;
    const int t = threadIdx.x;
    if (blk < 32) {
        int idx = blk * 256 + t;   // 0..8191
        int d = idx >> 6;          // 0..127
        int h = idx & 63;          // 0..63
        float w1 = W[d * H_ + h];
        float w2 = W[(D_ + d) * H_ + h];
        int kt = d >> 5, q = (d >> 3) & 3, j = d & 7;
        int nt = h >> 4, lm = h & 15;
        int lane = (q << 4) | lm;
        wfrag[((kt * 4 + nt) * 64 + lane) * 8 + j] = f2bf(w1 + w2);
    } else {
        int lane = t & 63, wv = t >> 6;
        int bb = (blk - 32) * 4 + wv;              // 0..2047
        const float* tg = target + (size_t)bb * D_;
        float acc = W_bias[lane];
        #pragma unroll 4
        for (int d = 0; d < D_; ++d) {
            float w2 = W[(D_ + d) * H_ + lane];
            float w3 = W[(2 * D_ + d) * H_ + lane];
            acc = fmaf(tg[d], w3 - w2, acc);
        }
        tproj[bb * H_ + lane] = acc;
    }
}

// ---------------------------------------------------------------------------
// K1: alpha[row] (raw score, pre-mask) for all 409600 rows via bf16 MFMA.
// Each wave: 16 rows x 64 hidden, K=128 -> 16 MFMAs. All 8 A-loads issued
// upfront (8 KB/wave in flight). Epilogue: +tproj, relu, dot O, quad reduce.
// O_bias is softmax-invariant -> skipped; mask applied in pool kernel.
// ---------------------------------------------------------------------------
__global__ __launch_bounds__(256) void alpha_kernel(const float* __restrict__ his,
                                                    const unsigned short* __restrict__ wfrag,
                                                    const float* __restrict__ tproj,
                                                    const float* __restrict__ Ovec,
                                                    float* __restrict__ alpha) {
    const int lane = threadIdx.x & 63;
    const int wv = threadIdx.x >> 6;
    const int tile = blockIdx.x * 4 + wv;
    const int row0 = tile * 16;
    const int lm = lane & 15;
    const int q = lane >> 4;

    // A: issue all 8 global float4 loads first (MLP)
    const float* hp = his + (size_t)(row0 + lm) * D_ + q * 8;
    float4 x[8];
    #pragma unroll
    for (int kt = 0; kt < 4; ++kt) {
        x[2 * kt]     = *(const float4*)(hp + kt * 32);
        x[2 * kt + 1] = *(const float4*)(hp + kt * 32 + 4);
    }

    // B fragments: 16 x 16B per lane, L2-resident (16 KB shared by all blocks)
    short8_t bfrag[16];
    #pragma unroll
    for (int f = 0; f < 16; ++f)
        bfrag[f] = *(const short8_t*)(wfrag + ((size_t)(f * 64 + lane)) * 8);

    f32x4 acc[4];
    #pragma unroll
    for (int nt = 0; nt < 4; ++nt) acc[nt] = (f32x4){0.f, 0.f, 0.f, 0.f};

    #pragma unroll
    for (int kt = 0; kt < 4; ++kt) {
        short8_t a;
        a[0] = f2bf(x[2*kt].x); a[1] = f2bf(x[2*kt].y);
        a[2] = f2bf(x[2*kt].z); a[3] = f2bf(x[2*kt].w);
        a[4] = f2bf(x[2*kt+1].x); a[5] = f2bf(x[2*kt+1].y);
        a[6] = f2bf(x[2*kt+1].z); a[7] = f2bf(x[2*kt+1].w);
        #pragma unroll
        for (int nt = 0; nt < 4; ++nt)
            acc[nt] = __builtin_amdgcn_mfma_f32_16x16x32_bf16(a, bfrag[kt * 4 + nt], acc[nt], 0, 0, 0);
    }

    // Epilogue. C layout: col(n) = nt*16 + lm, row(m) = q*4 + r.
    float part[4];
    #pragma unroll
    for (int r = 0; r < 4; ++r) {
        int grow = row0 + q * 4 + r;
        int b = grow / S_;
        const float* tp = tproj + b * H_;
        float sum = 0.f;
        #pragma unroll
        for (int nt = 0; nt < 4; ++nt) {
            int h = nt * 16 + lm;
            float v = acc[nt][r] + tp[h];
            v = fmaxf(v, 0.f);
            sum = fmaf(v, Ovec[h], sum);
        }
        part[r] = sum;
    }
    #pragma unroll
    for (int off = 1; off < 16; off <<= 1) {
        #pragma unroll
        for (int r = 0; r < 4; ++r)
            part[r] += __shfl_xor(part[r], off);
    }
    if (lm == 0) {
        #pragma unroll
        for (int r = 0; r < 4; ++r)
            alpha[row0 + q * 4 + r] = part[r];
    }
}

// ---------------------------------------------------------------------------
// K2: per-batch mask+softmax over alpha[b,:], then pool from GLOBAL fp32 his.
// Tiny LDS + low VGPR -> whole 2048-block grid co-resident (32 waves/CU).
// Pool pattern: thread (sg = t>>5, d4 = t&31) -> 25 independent float4 loads,
// 1 KB/instruction coalescing (rows s and s+1 adjacent within a wave).
// ---------------------------------------------------------------------------
__global__ __launch_bounds__(256) void pool_kernel(const float* __restrict__ his,
                                                   const float* __restrict__ alpha,
                                                   const float* __restrict__ mask,
                                                   float* __restrict__ out) {
    __shared__ float wgt[S_];
    __shared__ float red8[8];
    __shared__ float pool_s[3 * D_];

    const int b    = blockIdx.x;
    const int t    = threadIdx.x;
    const int lane = t & 63;
    const int wv   = t >> 6;

    // ---- masked softmax over s = 0..199 ----
    float a = -INFINITY;
    if (t < S_)
        a = alpha[(size_t)b * S_ + t] - mask[(size_t)b * S_ + t] * MASK_SCALE;
    float m = a;
    #pragma unroll
    for (int off = 1; off < 64; off <<= 1) m = fmaxf(m, __shfl_xor(m, off));
    if (lane == 0) red8[wv] = m;
    __syncthreads();
    m = fmaxf(fmaxf(red8[0], red8[1]), fmaxf(red8[2], red8[3]));
    float e = (t < S_) ? __expf(a - m) : 0.f;
    float ssum = e;
    #pragma unroll
    for (int off = 1; off < 64; off <<= 1) ssum += __shfl_xor(ssum, off);
    if (lane == 0) red8[4 + wv] = ssum;
    __syncthreads();
    float inv = 1.f / (red8[4] + red8[5] + red8[6] + red8[7]);
    if (t < S_) wgt[t] = e * inv;
    __syncthreads();

    // ---- pooling from global fp32 his ----
    const int d4 = t & 31;           // float4 chunk: d = d4*4 .. d4*4+3
    const int sg = t >> 5;           // 0..7 s-groups
    const float4* hb4 = (const float4*)(his + (size_t)b * S_ * D_);
    float acc0 = 0.f, acc1 = 0.f, acc2 = 0.f, acc3 = 0.f;
    #pragma unroll 5
    for (int s = sg; s < S_; s += 8) {
        float w = wgt[s];            // half-wave-uniform broadcast
        float4 v = hb4[s * 32 + d4];
        acc0 = fmaf(w, v.x, acc0);
        acc1 = fmaf(w, v.y, acc1);
        acc2 = fmaf(w, v.z, acc2);
        acc3 = fmaf(w, v.w, acc3);
    }
    // combine the two s-groups within each wave
    acc0 += __shfl_xor(acc0, 32);
    acc1 += __shfl_xor(acc1, 32);
    acc2 += __shfl_xor(acc2, 32);
    acc3 += __shfl_xor(acc3, 32);
    if (wv && lane < 32) {
        float4 p; p.x = acc0; p.y = acc1; p.z = acc2; p.w = acc3;
        *(float4*)(&pool_s[(wv - 1) * D_ + d4 * 4]) = p;
    }
    __syncthreads();
    if (wv == 0 && lane < 32) {
        #pragma unroll
        for (int k = 0; k < 3; ++k) {
            const float4 p = *(const float4*)(&pool_s[k * D_ + d4 * 4]);
            acc0 += p.x; acc1 += p.y; acc2 += p.z; acc3 += p.w;
        }
        float4 o; o.x = acc0; o.y = acc1; o.z = acc2; o.w = acc3;
        *(float4*)(out + (size_t)b * D_ + d4 * 4) = o;
    }
}

// ---------------------------------------------------------------------------
extern "C" void kernel_launch(void* const* d_in, const int* in_sizes, int n_in,
                              void* d_out, int out_size, void* d_ws, size_t ws_size,
                              hipStream_t stream) {
    const float* his    = (const float*)d_in[0];
    const float* target = (const float*)d_in[1];
    const float* mask   = (const float*)d_in[2];
    const float* W      = (const float*)d_in[3];
    const float* W_bias = (const float*)d_in[4];
    const float* Ovec   = (const float*)d_in[5];
    // O_bias (d_in[6]) is softmax-invariant -> unused
    float* out = (float*)d_out;

    char* ws = (char*)d_ws;
    unsigned short* wfrag = (unsigned short*)ws;            // 16 KB
    float* tproj          = (float*)(ws + 16384);           // 512 KB
    float* alpha          = (float*)(ws + 16384 + 524288);  // 1.6 MB

    prep<<<544, 256, 0, stream>>>(W, W_bias, target, wfrag, tproj);
    alpha_kernel<<<ROWS / 64, 256, 0, stream>>>(his, wfrag, tproj, Ovec, alpha);
    pool_kernel<<<B_, 256, 0, stream>>>(his, alpha, mask, out);
}